// Round 2
// baseline (1123.995 us; speedup 1.0000x reference)
//
#include <hip/hip_runtime.h>
#include <math.h>

#define T_TOK 25600   // B*L = 128*200
#define HDIM  128
#define SEQL  200
#define PAIRS (T_TOK * 2)   // 51200 (token, slot) routing pairs
#define PTILES 808          // max 64-row tiles after per-expert 64-alignment

__device__ __forceinline__ float wave_sum64(float v) {
#pragma unroll
  for (int off = 32; off > 0; off >>= 1) v += __shfl_xor(v, off, 64);
  return v;
}

// ---------------- item gather + pos + LayerNorm(eps=1e-12) ----------------
__global__ __launch_bounds__(256) void seq_ln_kernel(
    const int* __restrict__ ids, const float* __restrict__ item,
    const float* __restrict__ pos, const float* __restrict__ lw,
    const float* __restrict__ lb, float* __restrict__ seq) {
  const int lane = threadIdx.x & 63;
  const int tok  = blockIdx.x * 4 + (threadIdx.x >> 6);
  const int id   = ids[tok];
  const int pl   = tok % SEQL;
  float x0 = item[(size_t)id * HDIM + lane]      + pos[pl * HDIM + lane];
  float x1 = item[(size_t)id * HDIM + 64 + lane] + pos[pl * HDIM + 64 + lane];
  float mean = wave_sum64(x0 + x1) * (1.0f / HDIM);
  float d0 = x0 - mean, d1 = x1 - mean;
  float var = wave_sum64(d0 * d0 + d1 * d1) * (1.0f / HDIM);
  float inv = rsqrtf(var + 1e-12f);
  seq[(size_t)tok * HDIM + lane]      = d0 * inv * lw[lane] + lb[lane];
  seq[(size_t)tok * HDIM + 64 + lane] = d1 * inv * lw[64 + lane] + lb[64 + lane];
}

// ---------------- row-wise l2 normalize, in place ----------------
__global__ __launch_bounds__(256) void l2norm_kernel(float* __restrict__ X) {
  const int lane = threadIdx.x & 63;
  const int tok  = blockIdx.x * 4 + (threadIdx.x >> 6);
  float x0 = X[(size_t)tok * HDIM + lane];
  float x1 = X[(size_t)tok * HDIM + 64 + lane];
  float s  = wave_sum64(x0 * x0 + x1 * x1);
  float sc = 1.0f / fmaxf(sqrtf(s), 1e-12f);
  X[(size_t)tok * HDIM + lane]      = x0 * sc;
  X[(size_t)tok * HDIM + 64 + lane] = x1 * sc;
}

// ---------------- generic GEMM  C[T,128] = A(rows)[.,K] @ W[128,K]^T + bias -------
// A rows optionally gathered via idx. BM=64, BN=128, BK=32, 256 threads.
// Thread (tm,tn) owns output cols {tn*4..+3} and {64+tn*4..+3}  (bank-conflict-free Ws reads)
__global__ __launch_bounds__(256) void gemm_bt_kernel(
    const float* __restrict__ A, const int* __restrict__ idx,
    const float* __restrict__ W, const float* __restrict__ bias,
    float* __restrict__ C, int K, int lda) {
  __shared__ float As[64][33];
  __shared__ float Ws[32][128];
  const int t = threadIdx.x;
  const int tile = blockIdx.x;
  const int tm = t >> 4, tn = t & 15;
  const int am = t >> 2, ak = (t & 3) * 8;
  const int wn = t >> 1, wk = (t & 1) * 16;
  const int arow = tile * 64 + am;
  const float* Arow = A + (size_t)(idx ? idx[arow] : arow) * lda;
  const float* Wrow = W + (size_t)wn * K + wk;

  float acc[4][8];
#pragma unroll
  for (int i = 0; i < 4; i++)
#pragma unroll
    for (int j = 0; j < 8; j++) acc[i][j] = 0.0f;

  for (int kb = 0; kb < K; kb += 32) {
    float4 a0 = *(const float4*)(Arow + kb + ak);
    float4 a1 = *(const float4*)(Arow + kb + ak + 4);
    float4 w0 = *(const float4*)(Wrow + kb);
    float4 w1 = *(const float4*)(Wrow + kb + 4);
    float4 w2 = *(const float4*)(Wrow + kb + 8);
    float4 w3 = *(const float4*)(Wrow + kb + 12);
    __syncthreads();
    As[am][ak + 0] = a0.x; As[am][ak + 1] = a0.y; As[am][ak + 2] = a0.z; As[am][ak + 3] = a0.w;
    As[am][ak + 4] = a1.x; As[am][ak + 5] = a1.y; As[am][ak + 6] = a1.z; As[am][ak + 7] = a1.w;
    Ws[wk +  0][wn] = w0.x; Ws[wk +  1][wn] = w0.y; Ws[wk +  2][wn] = w0.z; Ws[wk +  3][wn] = w0.w;
    Ws[wk +  4][wn] = w1.x; Ws[wk +  5][wn] = w1.y; Ws[wk +  6][wn] = w1.z; Ws[wk +  7][wn] = w1.w;
    Ws[wk +  8][wn] = w2.x; Ws[wk +  9][wn] = w2.y; Ws[wk + 10][wn] = w2.z; Ws[wk + 11][wn] = w2.w;
    Ws[wk + 12][wn] = w3.x; Ws[wk + 13][wn] = w3.y; Ws[wk + 14][wn] = w3.z; Ws[wk + 15][wn] = w3.w;
    __syncthreads();
#pragma unroll
    for (int kk = 0; kk < 32; kk++) {
      float av[4];
#pragma unroll
      for (int i = 0; i < 4; i++) av[i] = As[tm * 4 + i][kk];
      float4 wv0 = *(const float4*)&Ws[kk][tn * 4];
      float4 wv1 = *(const float4*)&Ws[kk][64 + tn * 4];
      float wv[8] = {wv0.x, wv0.y, wv0.z, wv0.w, wv1.x, wv1.y, wv1.z, wv1.w};
#pragma unroll
      for (int i = 0; i < 4; i++)
#pragma unroll
        for (int j = 0; j < 8; j++) acc[i][j] += av[i] * wv[j];
    }
  }
  float bj[8];
#pragma unroll
  for (int j = 0; j < 4; j++) { bj[j] = bias[tn * 4 + j]; bj[4 + j] = bias[64 + tn * 4 + j]; }
#pragma unroll
  for (int i = 0; i < 4; i++) {
    const int row = tile * 64 + tm * 4 + i;
    float* Crow = C + (size_t)row * 128;
    float4 o0 = make_float4(acc[i][0] + bj[0], acc[i][1] + bj[1], acc[i][2] + bj[2], acc[i][3] + bj[3]);
    float4 o1 = make_float4(acc[i][4] + bj[4], acc[i][5] + bj[5], acc[i][6] + bj[6], acc[i][7] + bj[7]);
    *(float4*)(Crow + tn * 4)      = o0;
    *(float4*)(Crow + 64 + tn * 4) = o1;
  }
}

// ---------------- fused mu/sg GEMMs + VAE reparam ----------------
// z[row] = (A@Wmu^T + bmu) + exp(A@Wsg^T + bsg) * noise   (K=N=128)
__global__ __launch_bounds__(256) void musgvae_kernel(
    const float* __restrict__ A, const float* __restrict__ Wmu,
    const float* __restrict__ bmu, const float* __restrict__ Wsg,
    const float* __restrict__ bsg, const float* __restrict__ noise,
    float* __restrict__ Z) {
  __shared__ float As[64][132];   // full K=128 A tile, staged once, b128 writes
  __shared__ float Ws[32][128];
  const int t = threadIdx.x;
  const int tile = blockIdx.x;
  const int tm = t >> 4, tn = t & 15;
  const int am = t >> 2, ak0 = (t & 3) * 32;
  const int wn = t >> 1, wk = (t & 1) * 16;

  const float* Arow = A + (size_t)(tile * 64 + am) * 128;
#pragma unroll
  for (int q = 0; q < 32; q += 4)
    *(float4*)&As[am][ak0 + q] = *(const float4*)(Arow + ak0 + q);

  float macc[4][8], sacc[4][8];
#pragma unroll
  for (int i = 0; i < 4; i++)
#pragma unroll
    for (int j = 0; j < 8; j++) { macc[i][j] = 0.0f; sacc[i][j] = 0.0f; }

  // pass 0: mu
  for (int kb = 0; kb < 128; kb += 32) {
    const float* Wrow = Wmu + (size_t)wn * 128 + kb + wk;
    float4 w0 = *(const float4*)(Wrow);
    float4 w1 = *(const float4*)(Wrow + 4);
    float4 w2 = *(const float4*)(Wrow + 8);
    float4 w3 = *(const float4*)(Wrow + 12);
    __syncthreads();
    Ws[wk +  0][wn] = w0.x; Ws[wk +  1][wn] = w0.y; Ws[wk +  2][wn] = w0.z; Ws[wk +  3][wn] = w0.w;
    Ws[wk +  4][wn] = w1.x; Ws[wk +  5][wn] = w1.y; Ws[wk +  6][wn] = w1.z; Ws[wk +  7][wn] = w1.w;
    Ws[wk +  8][wn] = w2.x; Ws[wk +  9][wn] = w2.y; Ws[wk + 10][wn] = w2.z; Ws[wk + 11][wn] = w2.w;
    Ws[wk + 12][wn] = w3.x; Ws[wk + 13][wn] = w3.y; Ws[wk + 14][wn] = w3.z; Ws[wk + 15][wn] = w3.w;
    __syncthreads();
#pragma unroll
    for (int kk = 0; kk < 32; kk++) {
      float av[4];
#pragma unroll
      for (int i = 0; i < 4; i++) av[i] = As[tm * 4 + i][kb + kk];
      float4 wv0 = *(const float4*)&Ws[kk][tn * 4];
      float4 wv1 = *(const float4*)&Ws[kk][64 + tn * 4];
      float wv[8] = {wv0.x, wv0.y, wv0.z, wv0.w, wv1.x, wv1.y, wv1.z, wv1.w};
#pragma unroll
      for (int i = 0; i < 4; i++)
#pragma unroll
        for (int j = 0; j < 8; j++) macc[i][j] += av[i] * wv[j];
    }
  }
  // pass 1: sg
  for (int kb = 0; kb < 128; kb += 32) {
    const float* Wrow = Wsg + (size_t)wn * 128 + kb + wk;
    float4 w0 = *(const float4*)(Wrow);
    float4 w1 = *(const float4*)(Wrow + 4);
    float4 w2 = *(const float4*)(Wrow + 8);
    float4 w3 = *(const float4*)(Wrow + 12);
    __syncthreads();
    Ws[wk +  0][wn] = w0.x; Ws[wk +  1][wn] = w0.y; Ws[wk +  2][wn] = w0.z; Ws[wk +  3][wn] = w0.w;
    Ws[wk +  4][wn] = w1.x; Ws[wk +  5][wn] = w1.y; Ws[wk +  6][wn] = w1.z; Ws[wk +  7][wn] = w1.w;
    Ws[wk +  8][wn] = w2.x; Ws[wk +  9][wn] = w2.y; Ws[wk + 10][wn] = w2.z; Ws[wk + 11][wn] = w2.w;
    Ws[wk + 12][wn] = w3.x; Ws[wk + 13][wn] = w3.y; Ws[wk + 14][wn] = w3.z; Ws[wk + 15][wn] = w3.w;
    __syncthreads();
#pragma unroll
    for (int kk = 0; kk < 32; kk++) {
      float av[4];
#pragma unroll
      for (int i = 0; i < 4; i++) av[i] = As[tm * 4 + i][kb + kk];
      float4 wv0 = *(const float4*)&Ws[kk][tn * 4];
      float4 wv1 = *(const float4*)&Ws[kk][64 + tn * 4];
      float wv[8] = {wv0.x, wv0.y, wv0.z, wv0.w, wv1.x, wv1.y, wv1.z, wv1.w};
#pragma unroll
      for (int i = 0; i < 4; i++)
#pragma unroll
        for (int j = 0; j < 8; j++) sacc[i][j] += av[i] * wv[j];
    }
  }

  float bm[8], bs[8];
#pragma unroll
  for (int j = 0; j < 4; j++) {
    bm[j]     = bmu[tn * 4 + j];      bs[j]     = bsg[tn * 4 + j];
    bm[4 + j] = bmu[64 + tn * 4 + j]; bs[4 + j] = bsg[64 + tn * 4 + j];
  }
#pragma unroll
  for (int i = 0; i < 4; i++) {
    const int row = tile * 64 + tm * 4 + i;
    const float* nr = noise + (size_t)row * 128;
    float* zr = Z + (size_t)row * 128;
    float4 n0 = *(const float4*)(nr + tn * 4);
    float4 n1 = *(const float4*)(nr + 64 + tn * 4);
    float nn[8] = {n0.x, n0.y, n0.z, n0.w, n1.x, n1.y, n1.z, n1.w};
    float o[8];
#pragma unroll
    for (int j = 0; j < 8; j++)
      o[j] = (macc[i][j] + bm[j]) + expf(sacc[i][j] + bs[j]) * nn[j];
    *(float4*)(zr + tn * 4)      = make_float4(o[0], o[1], o[2], o[3]);
    *(float4*)(zr + 64 + tn * 4) = make_float4(o[4], o[5], o[6], o[7]);
  }
}

// ---------------- softmax gate -> top2 -> renormalize -> (idx, weight) pairs ---
__global__ __launch_bounds__(256) void gate2_kernel(
    const float* __restrict__ Z, const float* __restrict__ GW,
    const float* __restrict__ GB, int* __restrict__ idx2,
    float* __restrict__ pw) {
  const int lane = threadIdx.x & 63;
  const int tok  = blockIdx.x * 4 + (threadIdx.x >> 6);
  float z0 = Z[(size_t)tok * HDIM + lane];
  float z1 = Z[(size_t)tok * HDIM + 64 + lane];
  float p[8];
#pragma unroll
  for (int e = 0; e < 8; e++)
    p[e] = z0 * GW[e * HDIM + lane] + z1 * GW[e * HDIM + 64 + lane];
#pragma unroll
  for (int off = 32; off > 0; off >>= 1)
#pragma unroll
    for (int e = 0; e < 8; e++) p[e] += __shfl_xor(p[e], off, 64);
  if (lane == 0) {
    float lg[8];
    float m = -1e30f;
#pragma unroll
    for (int e = 0; e < 8; e++) { lg[e] = p[e] + GB[e]; m = fmaxf(m, lg[e]); }
    float ex[8], s = 0.0f;
#pragma unroll
    for (int e = 0; e < 8; e++) { ex[e] = expf(lg[e] - m); s += ex[e]; }
    int i1 = 0;
#pragma unroll
    for (int e = 1; e < 8; e++) if (ex[e] > ex[i1]) i1 = e;
    int i2 = (i1 == 0) ? 1 : 0;
#pragma unroll
    for (int e = 0; e < 8; e++) if (e != i1 && ex[e] > ex[i2]) i2 = e;
    float w1 = ex[i1] / s, w2 = ex[i2] / s;
    float d = w1 + w2 + 1e-8f;
    idx2[tok * 2]     = i1;
    idx2[tok * 2 + 1] = i2;
    pw[tok * 2]       = w1 / d;
    pw[tok * 2 + 1]   = w2 / d;
  }
}

// ---------------- routing metadata in ONE kernel ----------------
// meta[0:8]=hist, [8:16]=cursors(0), [16:24]=64-aligned offsets, [24]=total
__global__ __launch_bounds__(256) void route_prep_kernel(
    const int* __restrict__ idx2, int* __restrict__ meta) {
  __shared__ int h[8];
  const int t = threadIdx.x;
  if (t < 8) h[t] = 0;
  __syncthreads();
  int c0 = 0, c1 = 0, c2 = 0, c3 = 0, c4 = 0, c5 = 0, c6 = 0, c7 = 0;
  for (int i = t; i < PAIRS; i += 256) {
    const int v = idx2[i];
    c0 += (v == 0); c1 += (v == 1); c2 += (v == 2); c3 += (v == 3);
    c4 += (v == 4); c5 += (v == 5); c6 += (v == 6); c7 += (v == 7);
  }
  atomicAdd(&h[0], c0); atomicAdd(&h[1], c1); atomicAdd(&h[2], c2); atomicAdd(&h[3], c3);
  atomicAdd(&h[4], c4); atomicAdd(&h[5], c5); atomicAdd(&h[6], c6); atomicAdd(&h[7], c7);
  __syncthreads();
  if (t == 0) {
    int o = 0;
#pragma unroll
    for (int e = 0; e < 8; e++) {
      meta[e] = h[e];
      meta[8 + e] = 0;
      meta[16 + e] = o;
      o += (h[e] + 63) & ~63;
    }
    meta[24] = o;
  }
}

__global__ __launch_bounds__(256) void scatter_kernel(
    const int* __restrict__ idx2, int* __restrict__ meta,
    int* __restrict__ pairs) {
  const int i = blockIdx.x * 256 + threadIdx.x;
  const int lane = threadIdx.x & 63;
  const int e = idx2[i];
#pragma unroll
  for (int ee = 0; ee < 8; ee++) {
    unsigned long long m = __ballot(e == ee);
    if (m == 0ull) continue;
    const int leader = __ffsll((long long)m) - 1;
    int base = 0;
    if (lane == leader) base = atomicAdd(&meta[8 + ee], (int)__popcll(m));
    base = __shfl(base, leader, 64);
    if (e == ee) {
      int rank = (int)__popcll(m & ((1ull << lane) - 1ull));
      pairs[meta[16 + ee] + base + rank] = i;
    }
  }
}

// ---------------- grouped top-2 expert GEMM ----------------
// For each 64-row tile of one expert's pair list:
//   tmp[p] = g_p * (Z[p>>1] @ W_e^T + b_e)
__global__ __launch_bounds__(256) void expert_grouped_kernel(
    const float* __restrict__ Z, const float* __restrict__ Wexp,
    const float* __restrict__ Bexp, const int* __restrict__ pairs,
    const float* __restrict__ pw, const int* __restrict__ meta,
    float* __restrict__ tmp) {
  const int base = blockIdx.x * 64;
  if (base >= meta[24]) return;       // uniform per block
  int e = 0;
#pragma unroll
  for (int k = 1; k < 8; k++) if (base >= meta[16 + k]) e = k;
  const int seg = meta[16 + e];
  const int cnt = meta[e];

  __shared__ float As[64][132];
  __shared__ float Ws[32][128];
  const int t = threadIdx.x;
  const int tm = t >> 4, tn = t & 15;
  const int am = t >> 2, ak0 = (t & 3) * 32;
  const int wn = t >> 1, wk = (t & 1) * 16;

  const int slotA = base + am;
  const int pA = (slotA - seg < cnt) ? pairs[slotA] : 0;
  const float* Zrow = Z + (size_t)(pA >> 1) * 128;
#pragma unroll
  for (int q = 0; q < 32; q += 4)
    *(float4*)&As[am][ak0 + q] = *(const float4*)(Zrow + ak0 + q);

  float acc[4][8];
#pragma unroll
  for (int i = 0; i < 4; i++)
#pragma unroll
    for (int j = 0; j < 8; j++) acc[i][j] = 0.0f;

  for (int kb = 0; kb < 128; kb += 32) {
    const float* Wrow = Wexp + ((size_t)e * 128 + wn) * 128 + kb + wk;
    float4 w0 = *(const float4*)(Wrow);
    float4 w1 = *(const float4*)(Wrow + 4);
    float4 w2 = *(const float4*)(Wrow + 8);
    float4 w3 = *(const float4*)(Wrow + 12);
    __syncthreads();
    Ws[wk +  0][wn] = w0.x; Ws[wk +  1][wn] = w0.y; Ws[wk +  2][wn] = w0.z; Ws[wk +  3][wn] = w0.w;
    Ws[wk +  4][wn] = w1.x; Ws[wk +  5][wn] = w1.y; Ws[wk +  6][wn] = w1.z; Ws[wk +  7][wn] = w1.w;
    Ws[wk +  8][wn] = w2.x; Ws[wk +  9][wn] = w2.y; Ws[wk + 10][wn] = w2.z; Ws[wk + 11][wn] = w2.w;
    Ws[wk + 12][wn] = w3.x; Ws[wk + 13][wn] = w3.y; Ws[wk + 14][wn] = w3.z; Ws[wk + 15][wn] = w3.w;
    __syncthreads();
#pragma unroll
    for (int kk = 0; kk < 32; kk++) {
      float av[4];
#pragma unroll
      for (int i = 0; i < 4; i++) av[i] = As[tm * 4 + i][kb + kk];
      float4 wv0 = *(const float4*)&Ws[kk][tn * 4];
      float4 wv1 = *(const float4*)&Ws[kk][64 + tn * 4];
      float wv[8] = {wv0.x, wv0.y, wv0.z, wv0.w, wv1.x, wv1.y, wv1.z, wv1.w};
#pragma unroll
      for (int i = 0; i < 4; i++)
#pragma unroll
        for (int j = 0; j < 8; j++) acc[i][j] += av[i] * wv[j];
    }
  }
  float be[8];
#pragma unroll
  for (int j = 0; j < 4; j++) {
    be[j]     = Bexp[e * 128 + tn * 4 + j];
    be[4 + j] = Bexp[e * 128 + 64 + tn * 4 + j];
  }
#pragma unroll
  for (int i = 0; i < 4; i++) {
    const int slot = base + tm * 4 + i;
    if (slot - seg < cnt) {
      const int p = pairs[slot];
      const float g = pw[p];
      float* orow = tmp + (size_t)p * 128;
      *(float4*)(orow + tn * 4) =
          make_float4(g * (acc[i][0] + be[0]), g * (acc[i][1] + be[1]),
                      g * (acc[i][2] + be[2]), g * (acc[i][3] + be[3]));
      *(float4*)(orow + 64 + tn * 4) =
          make_float4(g * (acc[i][4] + be[4]), g * (acc[i][5] + be[5]),
                      g * (acc[i][6] + be[6]), g * (acc[i][7] + be[7]));
    }
  }
}

// ---------------- combine the two expert slots per token into cat ----------------
__global__ __launch_bounds__(256) void combine_kernel(
    const float* __restrict__ tmp, float* __restrict__ cat, int col_off) {
  const int lane = threadIdx.x & 63;
  const int tok  = blockIdx.x * 4 + (threadIdx.x >> 6);
  const float* r0 = tmp + (size_t)tok * 256;
  const float* r1 = r0 + 128;
  cat[(size_t)tok * 256 + col_off + lane]      = r0[lane] + r1[lane];
  cat[(size_t)tok * 256 + col_off + 64 + lane] = r0[64 + lane] + r1[64 + lane];
}

// ---------------- final: out = seq + relu(LN(y, eps=1e-5)*w+b) ----------------
__global__ __launch_bounds__(256) void fusion_ln_kernel(
    const float* __restrict__ y, const float* __restrict__ seq,
    const float* __restrict__ lw, const float* __restrict__ lb,
    float* __restrict__ out) {
  const int lane = threadIdx.x & 63;
  const int tok  = blockIdx.x * 4 + (threadIdx.x >> 6);
  float x0 = y[(size_t)tok * HDIM + lane];
  float x1 = y[(size_t)tok * HDIM + 64 + lane];
  float mean = wave_sum64(x0 + x1) * (1.0f / HDIM);
  float d0 = x0 - mean, d1 = x1 - mean;
  float var = wave_sum64(d0 * d0 + d1 * d1) * (1.0f / HDIM);
  float inv = rsqrtf(var + 1e-5f);
  float h0 = fmaxf(d0 * inv * lw[lane] + lb[lane], 0.0f);
  float h1 = fmaxf(d1 * inv * lw[64 + lane] + lb[64 + lane], 0.0f);
  out[(size_t)tok * HDIM + lane]      = seq[(size_t)tok * HDIM + lane] + h0;
  out[(size_t)tok * HDIM + 64 + lane] = seq[(size_t)tok * HDIM + 64 + lane] + h1;
}

extern "C" void kernel_launch(void* const* d_in, const int* in_sizes, int n_in,
                              void* d_out, int out_size, void* d_ws, size_t ws_size,
                              hipStream_t stream) {
  const int*   ids     = (const int*)d_in[0];
  const float* t_noise = (const float*)d_in[1];
  const float* i_noise = (const float*)d_in[2];
  const float* item    = (const float*)d_in[3];
  const float* pos     = (const float*)d_in[4];
  const float* text    = (const float*)d_in[5];
  const float* img     = (const float*)d_in[6];
  const float* fct_w   = (const float*)d_in[7];
  const float* fct_b   = (const float*)d_in[8];
  const float* fci_w   = (const float*)d_in[9];
  const float* fci_b   = (const float*)d_in[10];
  const float* ln_w    = (const float*)d_in[11];
  const float* ln_b    = (const float*)d_in[12];
  const float* mu_t_w  = (const float*)d_in[13];
  const float* mu_t_b  = (const float*)d_in[14];
  const float* sg_t_w  = (const float*)d_in[15];
  const float* sg_t_b  = (const float*)d_in[16];
  const float* mu_i_w  = (const float*)d_in[17];
  const float* mu_i_b  = (const float*)d_in[18];
  const float* sg_i_w  = (const float*)d_in[19];
  const float* sg_i_b  = (const float*)d_in[20];
  const float* gate_w  = (const float*)d_in[21];
  const float* gate_b  = (const float*)d_in[22];
  const float* texp_w  = (const float*)d_in[23];
  const float* texp_b  = (const float*)d_in[24];
  const float* iexp_w  = (const float*)d_in[25];
  const float* iexp_b  = (const float*)d_in[26];
  const float* fus_w   = (const float*)d_in[27];
  const float* fus_b   = (const float*)d_in[28];
  const float* fus_lw  = (const float*)d_in[29];
  const float* fus_lb  = (const float*)d_in[30];
  float* out = (float*)d_out;

  float* ws = (float*)d_ws;
  const size_t TH = (size_t)T_TOK * HDIM;
  float* seq = ws;               // TH
  float* emb = ws + TH;          // TH  (text_emb, then img_emb, then fusion y)
  float* z   = ws + 2 * TH;      // TH  (t_z, then i_z)
  float* cat = ws + 3 * TH;      // 2*TH
  float* tmp = ws + 5 * TH;      // 2*TH (per-(token,slot) expert outputs)
  int*   idx2  = (int*)(ws + 7 * TH);            // PAIRS ints
  float* pwr   = ws + 7 * TH + PAIRS;            // PAIRS floats
  int*   pairs = (int*)(ws + 7 * TH + 2 * PAIRS);        // PAIRS + pad ints
  int*   meta  = (int*)(ws + 7 * TH + 3 * PAIRS + 512);  // 32 ints
  float* y = emb;

  const int tokW  = T_TOK / 4;   // 6400 blocks, one wave per token
  const int tiles = T_TOK / 64;  // 400 GEMM tiles
  const int pgrid = PAIRS / 256; // 200 blocks over routing pairs

  // 1. seq embedding + LN
  seq_ln_kernel<<<tokW, 256, 0, stream>>>(ids, item, pos, ln_w, ln_b, seq);

  // ---- text modality ----
  gemm_bt_kernel<<<tiles, 256, 0, stream>>>(text, ids, fct_w, fct_b, emb, 768, 768);
  l2norm_kernel<<<tokW, 256, 0, stream>>>(emb);
  musgvae_kernel<<<tiles, 256, 0, stream>>>(emb, mu_t_w, mu_t_b, sg_t_w, sg_t_b, t_noise, z);
  gate2_kernel<<<tokW, 256, 0, stream>>>(z, gate_w, gate_b, idx2, pwr);
  route_prep_kernel<<<1, 256, 0, stream>>>(idx2, meta);
  scatter_kernel<<<pgrid, 256, 0, stream>>>(idx2, meta, pairs);
  expert_grouped_kernel<<<PTILES, 256, 0, stream>>>(z, texp_w, texp_b, pairs, pwr, meta, tmp);
  combine_kernel<<<tokW, 256, 0, stream>>>(tmp, cat, 0);

  // ---- image modality ----
  gemm_bt_kernel<<<tiles, 256, 0, stream>>>(img, ids, fci_w, fci_b, emb, 512, 512);
  l2norm_kernel<<<tokW, 256, 0, stream>>>(emb);
  musgvae_kernel<<<tiles, 256, 0, stream>>>(emb, mu_i_w, mu_i_b, sg_i_w, sg_i_b, i_noise, z);
  gate2_kernel<<<tokW, 256, 0, stream>>>(z, gate_w, gate_b, idx2, pwr);
  route_prep_kernel<<<1, 256, 0, stream>>>(idx2, meta);
  scatter_kernel<<<pgrid, 256, 0, stream>>>(idx2, meta, pairs);
  expert_grouped_kernel<<<PTILES, 256, 0, stream>>>(z, iexp_w, iexp_b, pairs, pwr, meta, tmp);
  combine_kernel<<<tokW, 256, 0, stream>>>(tmp, cat, 128);

  // ---- fusion ----
  gemm_bt_kernel<<<tiles, 256, 0, stream>>>(cat, nullptr, fus_w, fus_b, y, 256, 256);
  fusion_ln_kernel<<<tokW, 256, 0, stream>>>(y, seq, fus_lw, fus_lb, out);
}

// Round 5
// 848.572 us; speedup vs baseline: 1.3246x; 1.3246x over previous
//
#include <hip/hip_runtime.h>
#include <math.h>

#define T_TOK 25600          // B*L = 128*200
#define HDIM  128
#define SEQL  200
#define PAIRS (T_TOK * 2)    // 51200 routing pairs
#define SEGCAP T_TOK         // max rows per expert segment
#define ETILES (T_TOK / 64)  // 400 tiles per expert
#define EGRID  (8 * ETILES)  // 3200 expert blocks (idle ones exit)

__device__ __forceinline__ float wave_sum64(float v) {
#pragma unroll
  for (int off = 32; off > 0; off >>= 1) v += __shfl_xor(v, off, 64);
  return v;
}

// ---------------- item gather + pos + LayerNorm(eps=1e-12) ----------------
__global__ __launch_bounds__(256) void seq_ln_kernel(
    const int* __restrict__ ids, const float* __restrict__ item,
    const float* __restrict__ pos, const float* __restrict__ lw,
    const float* __restrict__ lb, float* __restrict__ seq) {
  const int lane = threadIdx.x & 63;
  const int tok  = blockIdx.x * 4 + (threadIdx.x >> 6);
  const int id   = ids[tok];
  const int pl   = tok % SEQL;
  float x0 = item[(size_t)id * HDIM + lane]      + pos[pl * HDIM + lane];
  float x1 = item[(size_t)id * HDIM + 64 + lane] + pos[pl * HDIM + 64 + lane];
  float mean = wave_sum64(x0 + x1) * (1.0f / HDIM);
  float d0 = x0 - mean, d1 = x1 - mean;
  float var = wave_sum64(d0 * d0 + d1 * d1) * (1.0f / HDIM);
  float inv = rsqrtf(var + 1e-12f);
  seq[(size_t)tok * HDIM + lane]      = d0 * inv * lw[lane] + lb[lane];
  seq[(size_t)tok * HDIM + 64 + lane] = d1 * inv * lw[64 + lane] + lb[64 + lane];
}

// ---------------- generic GEMM  C[T,128] = A(rows)[.,K] @ W[128,K]^T + bias ----
// MODE 0: plain.  MODE 1: l2-normalize each output row in epilogue.
// MODE 2: A row t = tmpT[2t]+tmpT[2t+1] (cols 0..127) | tmpI[2t]+tmpI[2t+1] (128..255)
// BM=64, BN=128, BK=32, 256 threads. As transposed [k][row]; register prefetch.
template<int MODE>
__global__ __launch_bounds__(256) void gemm_bt_kernel(
    const float* __restrict__ A, const int* __restrict__ idx,
    const float* __restrict__ A2, const float* __restrict__ W,
    const float* __restrict__ bias, float* __restrict__ C,
    int K, int lda) {
  __shared__ float As[32][64];    // [k][row]
  __shared__ float Ws[32][128];   // [k][col]
  const int t = threadIdx.x;
  const int tile = blockIdx.x;
  const int tm = t >> 4, tn = t & 15;
  const int am = t >> 2, ak = (t & 3) * 8;
  const int wn = t >> 1, wk = (t & 1) * 16;
  const int arow = tile * 64 + am;
  const float* Arow = nullptr;
  if (MODE != 2) Arow = A + (size_t)(idx ? idx[arow] : arow) * lda;
  const float* Wrow = W + (size_t)wn * K + wk;

  float acc[4][8];
#pragma unroll
  for (int i = 0; i < 4; i++)
#pragma unroll
    for (int j = 0; j < 8; j++) acc[i][j] = 0.0f;

  float4 a0, a1, w0, w1, w2, w3;
  auto loadA = [&](int kb) {
    if (MODE == 2) {
      const int kba = kb + ak;
      const float* s = (kba < 128)
          ? A  + (size_t)(arow * 2) * 128 + kba
          : A2 + (size_t)(arow * 2) * 128 + (kba - 128);
      float4 p0 = *(const float4*)(s);
      float4 p1 = *(const float4*)(s + 4);
      float4 q0 = *(const float4*)(s + 128);
      float4 q1 = *(const float4*)(s + 132);
      a0 = make_float4(p0.x + q0.x, p0.y + q0.y, p0.z + q0.z, p0.w + q0.w);
      a1 = make_float4(p1.x + q1.x, p1.y + q1.y, p1.z + q1.z, p1.w + q1.w);
    } else {
      a0 = *(const float4*)(Arow + kb + ak);
      a1 = *(const float4*)(Arow + kb + ak + 4);
    }
  };
  auto loadW = [&](int kb) {
    w0 = *(const float4*)(Wrow + kb);
    w1 = *(const float4*)(Wrow + kb + 4);
    w2 = *(const float4*)(Wrow + kb + 8);
    w3 = *(const float4*)(Wrow + kb + 12);
  };

  loadA(0); loadW(0);
  for (int kb = 0; kb < K; kb += 32) {
    __syncthreads();
    As[ak + 0][am] = a0.x; As[ak + 1][am] = a0.y; As[ak + 2][am] = a0.z; As[ak + 3][am] = a0.w;
    As[ak + 4][am] = a1.x; As[ak + 5][am] = a1.y; As[ak + 6][am] = a1.z; As[ak + 7][am] = a1.w;
    Ws[wk +  0][wn] = w0.x; Ws[wk +  1][wn] = w0.y; Ws[wk +  2][wn] = w0.z; Ws[wk +  3][wn] = w0.w;
    Ws[wk +  4][wn] = w1.x; Ws[wk +  5][wn] = w1.y; Ws[wk +  6][wn] = w1.z; Ws[wk +  7][wn] = w1.w;
    Ws[wk +  8][wn] = w2.x; Ws[wk +  9][wn] = w2.y; Ws[wk + 10][wn] = w2.z; Ws[wk + 11][wn] = w2.w;
    Ws[wk + 12][wn] = w3.x; Ws[wk + 13][wn] = w3.y; Ws[wk + 14][wn] = w3.z; Ws[wk + 15][wn] = w3.w;
    __syncthreads();
    if (kb + 32 < K) { loadA(kb + 32); loadW(kb + 32); }  // prefetch hides latency
#pragma unroll
    for (int kk = 0; kk < 32; kk++) {
      float4 av4 = *(const float4*)&As[kk][tm * 4];
      float4 wv0 = *(const float4*)&Ws[kk][tn * 4];
      float4 wv1 = *(const float4*)&Ws[kk][64 + tn * 4];
      float av[4] = {av4.x, av4.y, av4.z, av4.w};
      float wv[8] = {wv0.x, wv0.y, wv0.z, wv0.w, wv1.x, wv1.y, wv1.z, wv1.w};
#pragma unroll
      for (int i = 0; i < 4; i++)
#pragma unroll
        for (int j = 0; j < 8; j++) acc[i][j] += av[i] * wv[j];
    }
  }
  float bj[8];
#pragma unroll
  for (int j = 0; j < 4; j++) { bj[j] = bias[tn * 4 + j]; bj[4 + j] = bias[64 + tn * 4 + j]; }
#pragma unroll
  for (int i = 0; i < 4; i++) {
    float o[8];
#pragma unroll
    for (int j = 0; j < 8; j++) o[j] = acc[i][j] + bj[j];
    if (MODE == 1) {
      float s = 0.0f;
#pragma unroll
      for (int j = 0; j < 8; j++) s += o[j] * o[j];
      s += __shfl_xor(s, 1, 64); s += __shfl_xor(s, 2, 64);
      s += __shfl_xor(s, 4, 64); s += __shfl_xor(s, 8, 64);
      float sc = 1.0f / fmaxf(sqrtf(s), 1e-12f);
#pragma unroll
      for (int j = 0; j < 8; j++) o[j] *= sc;
    }
    const int row = tile * 64 + tm * 4 + i;
    float* Crow = C + (size_t)row * 128;
    *(float4*)(Crow + tn * 4)      = make_float4(o[0], o[1], o[2], o[3]);
    *(float4*)(Crow + 64 + tn * 4) = make_float4(o[4], o[5], o[6], o[7]);
  }
}

// ---------------- fused mu/sg GEMMs + VAE reparam (K=N=128) ----------------
__global__ __launch_bounds__(256) void musgvae_kernel(
    const float* __restrict__ A, const float* __restrict__ Wmu,
    const float* __restrict__ bmu, const float* __restrict__ Wsg,
    const float* __restrict__ bsg, const float* __restrict__ noise,
    float* __restrict__ Z) {
  __shared__ float As[128][64];   // full K, transposed, staged once
  __shared__ float Ws[32][128];
  const int t = threadIdx.x;
  const int tile = blockIdx.x;
  const int tm = t >> 4, tn = t & 15;
  const int am = t >> 2, ak0 = (t & 3) * 32;
  const int wn = t >> 1, wk = (t & 1) * 16;

  {
    const float* Arow = A + (size_t)(tile * 64 + am) * 128 + ak0;
#pragma unroll
    for (int q = 0; q < 32; q += 4) {
      float4 v = *(const float4*)(Arow + q);
      As[ak0 + q + 0][am] = v.x; As[ak0 + q + 1][am] = v.y;
      As[ak0 + q + 2][am] = v.z; As[ak0 + q + 3][am] = v.w;
    }
  }

  float macc[4][8], sacc[4][8];
#pragma unroll
  for (int i = 0; i < 4; i++)
#pragma unroll
    for (int j = 0; j < 8; j++) { macc[i][j] = 0.0f; sacc[i][j] = 0.0f; }

  float4 w0, w1, w2, w3;
  auto loadW = [&](const float* Wsrc, int kb) {
    const float* p = Wsrc + (size_t)wn * 128 + kb + wk;
    w0 = *(const float4*)(p);
    w1 = *(const float4*)(p + 4);
    w2 = *(const float4*)(p + 8);
    w3 = *(const float4*)(p + 12);
  };
  auto pass = [&](const float* Wsrc, const float* Wnext, float (&accr)[4][8]) {
    for (int sb = 0; sb < 4; sb++) {
      const int kb = sb * 32;
      __syncthreads();
      Ws[wk +  0][wn] = w0.x; Ws[wk +  1][wn] = w0.y; Ws[wk +  2][wn] = w0.z; Ws[wk +  3][wn] = w0.w;
      Ws[wk +  4][wn] = w1.x; Ws[wk +  5][wn] = w1.y; Ws[wk +  6][wn] = w1.z; Ws[wk +  7][wn] = w1.w;
      Ws[wk +  8][wn] = w2.x; Ws[wk +  9][wn] = w2.y; Ws[wk + 10][wn] = w2.z; Ws[wk + 11][wn] = w2.w;
      Ws[wk + 12][wn] = w3.x; Ws[wk + 13][wn] = w3.y; Ws[wk + 14][wn] = w3.z; Ws[wk + 15][wn] = w3.w;
      __syncthreads();
      if (sb < 3) loadW(Wsrc, kb + 32);
      else if (Wnext) loadW(Wnext, 0);
#pragma unroll
      for (int kk = 0; kk < 32; kk++) {
        float4 av4 = *(const float4*)&As[kb + kk][tm * 4];
        float4 wv0 = *(const float4*)&Ws[kk][tn * 4];
        float4 wv1 = *(const float4*)&Ws[kk][64 + tn * 4];
        float av[4] = {av4.x, av4.y, av4.z, av4.w};
        float wv[8] = {wv0.x, wv0.y, wv0.z, wv0.w, wv1.x, wv1.y, wv1.z, wv1.w};
#pragma unroll
        for (int i = 0; i < 4; i++)
#pragma unroll
          for (int j = 0; j < 8; j++) accr[i][j] += av[i] * wv[j];
      }
    }
  };
  loadW(Wmu, 0);
  pass(Wmu, Wsg, macc);
  pass(Wsg, nullptr, sacc);

  float bm[8], bs[8];
#pragma unroll
  for (int j = 0; j < 4; j++) {
    bm[j]     = bmu[tn * 4 + j];      bs[j]     = bsg[tn * 4 + j];
    bm[4 + j] = bmu[64 + tn * 4 + j]; bs[4 + j] = bsg[64 + tn * 4 + j];
  }
#pragma unroll
  for (int i = 0; i < 4; i++) {
    const int row = tile * 64 + tm * 4 + i;
    const float* nr = noise + (size_t)row * 128;
    float* zr = Z + (size_t)row * 128;
    float4 n0 = *(const float4*)(nr + tn * 4);
    float4 n1 = *(const float4*)(nr + 64 + tn * 4);
    float nn[8] = {n0.x, n0.y, n0.z, n0.w, n1.x, n1.y, n1.z, n1.w};
    float o[8];
#pragma unroll
    for (int j = 0; j < 8; j++)
      o[j] = (macc[i][j] + bm[j]) + expf(sacc[i][j] + bs[j]) * nn[j];
    *(float4*)(zr + tn * 4)      = make_float4(o[0], o[1], o[2], o[3]);
    *(float4*)(zr + 64 + tn * 4) = make_float4(o[4], o[5], o[6], o[7]);
  }
}

// ---------------- softmax gate -> top2 -> renorm -> (idx, weight); zero cursors ---
__global__ __launch_bounds__(256) void gate2_kernel(
    const float* __restrict__ Z, const float* __restrict__ GW,
    const float* __restrict__ GB, int* __restrict__ idx2,
    float* __restrict__ pw, int* __restrict__ meta) {
  if (blockIdx.x == 0 && threadIdx.x < 8) meta[8 + threadIdx.x] = 0;
  const int lane = threadIdx.x & 63;
  const int tok  = blockIdx.x * 4 + (threadIdx.x >> 6);
  float z0 = Z[(size_t)tok * HDIM + lane];
  float z1 = Z[(size_t)tok * HDIM + 64 + lane];
  float p[8];
#pragma unroll
  for (int e = 0; e < 8; e++)
    p[e] = z0 * GW[e * HDIM + lane] + z1 * GW[e * HDIM + 64 + lane];
#pragma unroll
  for (int off = 32; off > 0; off >>= 1)
#pragma unroll
    for (int e = 0; e < 8; e++) p[e] += __shfl_xor(p[e], off, 64);
  if (lane == 0) {
    float lg[8];
    float m = -1e30f;
#pragma unroll
    for (int e = 0; e < 8; e++) { lg[e] = p[e] + GB[e]; m = fmaxf(m, lg[e]); }
    float ex[8], s = 0.0f;
#pragma unroll
    for (int e = 0; e < 8; e++) { ex[e] = expf(lg[e] - m); s += ex[e]; }
    int i1 = 0;
#pragma unroll
    for (int e = 1; e < 8; e++) if (ex[e] > ex[i1]) i1 = e;
    int i2 = (i1 == 0) ? 1 : 0;
#pragma unroll
    for (int e = 0; e < 8; e++) if (e != i1 && ex[e] > ex[i2]) i2 = e;
    float w1 = ex[i1] / s, w2 = ex[i2] / s;
    float d = w1 + w2 + 1e-8f;
    idx2[tok * 2]     = i1;
    idx2[tok * 2 + 1] = i2;
    pw[tok * 2]       = w1 / d;
    pw[tok * 2 + 1]   = w2 / d;
  }
}

// ---------------- scatter pairs into fixed per-expert segments ----------------
// meta[8+e] = running cursor -> final count. Block-aggregated atomics.
__global__ __launch_bounds__(256) void scatter_kernel(
    const int* __restrict__ idx2, int* __restrict__ meta,
    int* __restrict__ pairs) {
  __shared__ int wcnt[4][8];
  __shared__ int wbase[4][8];
  const int i = blockIdx.x * 256 + threadIdx.x;
  const int w = threadIdx.x >> 6;
  const int lane = threadIdx.x & 63;
  const int e = idx2[i];
  unsigned long long b0 = __ballot(e == 0), b1 = __ballot(e == 1);
  unsigned long long b2 = __ballot(e == 2), b3 = __ballot(e == 3);
  unsigned long long b4 = __ballot(e == 4), b5 = __ballot(e == 5);
  unsigned long long b6 = __ballot(e == 6), b7 = __ballot(e == 7);
  if (lane == 0) {
    wcnt[w][0] = (int)__popcll(b0); wcnt[w][1] = (int)__popcll(b1);
    wcnt[w][2] = (int)__popcll(b2); wcnt[w][3] = (int)__popcll(b3);
    wcnt[w][4] = (int)__popcll(b4); wcnt[w][5] = (int)__popcll(b5);
    wcnt[w][6] = (int)__popcll(b6); wcnt[w][7] = (int)__popcll(b7);
  }
  const unsigned long long lmask = (1ull << lane) - 1ull;
  unsigned long long be =
      e == 0 ? b0 : e == 1 ? b1 : e == 2 ? b2 : e == 3 ? b3 :
      e == 4 ? b4 : e == 5 ? b5 : e == 6 ? b6 : b7;
  const int rank = (int)__popcll(be & lmask);
  __syncthreads();
  if (threadIdx.x < 8) {
    const int ee = threadIdx.x;
    const int c0 = wcnt[0][ee], c1 = wcnt[1][ee], c2 = wcnt[2][ee], c3 = wcnt[3][ee];
    const int basev = atomicAdd(&meta[8 + ee], c0 + c1 + c2 + c3);
    wbase[0][ee] = basev;
    wbase[1][ee] = basev + c0;
    wbase[2][ee] = basev + c0 + c1;
    wbase[3][ee] = basev + c0 + c1 + c2;
  }
  __syncthreads();
  pairs[e * SEGCAP + wbase[w][e] + rank] = i;
}

// ---------------- grouped top-2 expert GEMM ----------------
// block -> (expert e, tile). tmp[p] = g_p * (Z[p>>1] @ W_e^T + b_e)
__global__ __launch_bounds__(256) void expert_grouped_kernel(
    const float* __restrict__ Z, const float* __restrict__ Wexp,
    const float* __restrict__ Bexp, const int* __restrict__ pairs,
    const float* __restrict__ pw, const int* __restrict__ meta,
    float* __restrict__ tmp) {
  const int e    = blockIdx.x / ETILES;
  const int til  = blockIdx.x - e * ETILES;
  const int cnt  = meta[8 + e];
  const int base = til * 64;
  if (base >= cnt) return;
  const int* seg = pairs + e * SEGCAP;

  __shared__ float As[128][64];
  __shared__ float Ws[32][128];
  const int t = threadIdx.x;
  const int tm = t >> 4, tn = t & 15;
  const int am = t >> 2, ak0 = (t & 3) * 32;
  const int wn = t >> 1, wk = (t & 1) * 16;

  const int slotA = base + am;
  const int pA = (slotA < cnt) ? seg[slotA] : 0;
  {
    const float* Zrow = Z + (size_t)(pA >> 1) * 128 + ak0;
#pragma unroll
    for (int q = 0; q < 32; q += 4) {
      float4 v = *(const float4*)(Zrow + q);
      As[ak0 + q + 0][am] = v.x; As[ak0 + q + 1][am] = v.y;
      As[ak0 + q + 2][am] = v.z; As[ak0 + q + 3][am] = v.w;
    }
  }

  float acc[4][8];
#pragma unroll
  for (int i = 0; i < 4; i++)
#pragma unroll
    for (int j = 0; j < 8; j++) acc[i][j] = 0.0f;

  const float* We = Wexp + (size_t)e * 128 * 128;
  float4 w0, w1, w2, w3;
  auto loadW = [&](int kb) {
    const float* p = We + (size_t)wn * 128 + kb + wk;
    w0 = *(const float4*)(p);
    w1 = *(const float4*)(p + 4);
    w2 = *(const float4*)(p + 8);
    w3 = *(const float4*)(p + 12);
  };
  loadW(0);
  for (int sb = 0; sb < 4; sb++) {
    const int kb = sb * 32;
    __syncthreads();
    Ws[wk +  0][wn] = w0.x; Ws[wk +  1][wn] = w0.y; Ws[wk +  2][wn] = w0.z; Ws[wk +  3][wn] = w0.w;
    Ws[wk +  4][wn] = w1.x; Ws[wk +  5][wn] = w1.y; Ws[wk +  6][wn] = w1.z; Ws[wk +  7][wn] = w1.w;
    Ws[wk +  8][wn] = w2.x; Ws[wk +  9][wn] = w2.y; Ws[wk + 10][wn] = w2.z; Ws[wk + 11][wn] = w2.w;
    Ws[wk + 12][wn] = w3.x; Ws[wk + 13][wn] = w3.y; Ws[wk + 14][wn] = w3.z; Ws[wk + 15][wn] = w3.w;
    __syncthreads();
    if (sb < 3) loadW(kb + 32);
#pragma unroll
    for (int kk = 0; kk < 32; kk++) {
      float4 av4 = *(const float4*)&As[kb + kk][tm * 4];
      float4 wv0 = *(const float4*)&Ws[kk][tn * 4];
      float4 wv1 = *(const float4*)&Ws[kk][64 + tn * 4];
      float av[4] = {av4.x, av4.y, av4.z, av4.w};
      float wv[8] = {wv0.x, wv0.y, wv0.z, wv0.w, wv1.x, wv1.y, wv1.z, wv1.w};
#pragma unroll
      for (int i = 0; i < 4; i++)
#pragma unroll
        for (int j = 0; j < 8; j++) acc[i][j] += av[i] * wv[j];
    }
  }
  float be8[8];
#pragma unroll
  for (int j = 0; j < 4; j++) {
    be8[j]     = Bexp[e * 128 + tn * 4 + j];
    be8[4 + j] = Bexp[e * 128 + 64 + tn * 4 + j];
  }
#pragma unroll
  for (int i = 0; i < 4; i++) {
    const int slot = base + tm * 4 + i;
    if (slot < cnt) {
      const int p = seg[slot];
      const float g = pw[p];
      float* orow = tmp + (size_t)p * 128;
      *(float4*)(orow + tn * 4) =
          make_float4(g * (acc[i][0] + be8[0]), g * (acc[i][1] + be8[1]),
                      g * (acc[i][2] + be8[2]), g * (acc[i][3] + be8[3]));
      *(float4*)(orow + 64 + tn * 4) =
          make_float4(g * (acc[i][4] + be8[4]), g * (acc[i][5] + be8[5]),
                      g * (acc[i][6] + be8[6]), g * (acc[i][7] + be8[7]));
    }
  }
}

// ---------------- final: out = seq + relu(LN(y, eps=1e-5)*w+b) ----------------
__global__ __launch_bounds__(256) void fusion_ln_kernel(
    const float* __restrict__ y, const float* __restrict__ seq,
    const float* __restrict__ lw, const float* __restrict__ lb,
    float* __restrict__ out) {
  const int lane = threadIdx.x & 63;
  const int tok  = blockIdx.x * 4 + (threadIdx.x >> 6);
  float x0 = y[(size_t)tok * HDIM + lane];
  float x1 = y[(size_t)tok * HDIM + 64 + lane];
  float mean = wave_sum64(x0 + x1) * (1.0f / HDIM);
  float d0 = x0 - mean, d1 = x1 - mean;
  float var = wave_sum64(d0 * d0 + d1 * d1) * (1.0f / HDIM);
  float inv = rsqrtf(var + 1e-5f);
  float h0 = fmaxf(d0 * inv * lw[lane] + lb[lane], 0.0f);
  float h1 = fmaxf(d1 * inv * lw[64 + lane] + lb[64 + lane], 0.0f);
  out[(size_t)tok * HDIM + lane]      = seq[(size_t)tok * HDIM + lane] + h0;
  out[(size_t)tok * HDIM + 64 + lane] = seq[(size_t)tok * HDIM + 64 + lane] + h1;
}

extern "C" void kernel_launch(void* const* d_in, const int* in_sizes, int n_in,
                              void* d_out, int out_size, void* d_ws, size_t ws_size,
                              hipStream_t stream) {
  const int*   ids     = (const int*)d_in[0];
  const float* t_noise = (const float*)d_in[1];
  const float* i_noise = (const float*)d_in[2];
  const float* item    = (const float*)d_in[3];
  const float* pos     = (const float*)d_in[4];
  const float* text    = (const float*)d_in[5];
  const float* img     = (const float*)d_in[6];
  const float* fct_w   = (const float*)d_in[7];
  const float* fct_b   = (const float*)d_in[8];
  const float* fci_w   = (const float*)d_in[9];
  const float* fci_b   = (const float*)d_in[10];
  const float* ln_w    = (const float*)d_in[11];
  const float* ln_b    = (const float*)d_in[12];
  const float* mu_t_w  = (const float*)d_in[13];
  const float* mu_t_b  = (const float*)d_in[14];
  const float* sg_t_w  = (const float*)d_in[15];
  const float* sg_t_b  = (const float*)d_in[16];
  const float* mu_i_w  = (const float*)d_in[17];
  const float* mu_i_b  = (const float*)d_in[18];
  const float* sg_i_w  = (const float*)d_in[19];
  const float* sg_i_b  = (const float*)d_in[20];
  const float* gate_w  = (const float*)d_in[21];
  const float* gate_b  = (const float*)d_in[22];
  const float* texp_w  = (const float*)d_in[23];
  const float* texp_b  = (const float*)d_in[24];
  const float* iexp_w  = (const float*)d_in[25];
  const float* iexp_b  = (const float*)d_in[26];
  const float* fus_w   = (const float*)d_in[27];
  const float* fus_b   = (const float*)d_in[28];
  const float* fus_lw  = (const float*)d_in[29];
  const float* fus_lb  = (const float*)d_in[30];
  float* out = (float*)d_out;

  float* ws = (float*)d_ws;
  const size_t TH = (size_t)T_TOK * HDIM;
  float* seq  = ws;                // TH
  float* emb  = ws + TH;           // TH  (text_emb / img_emb / fusion y)
  float* z    = ws + 2 * TH;       // TH
  float* tmpT = ws + 3 * TH;       // 2*TH
  float* tmpI = ws + 5 * TH;       // 2*TH
  int*   idx2  = (int*)(ws + 7 * TH);                      // PAIRS
  float* pwr   = ws + 7 * TH + PAIRS;                      // PAIRS
  int*   pairs = (int*)(ws + 7 * TH + 2 * PAIRS);          // 8*SEGCAP
  int*   meta  = (int*)(ws + 7 * TH + 2 * PAIRS + 8 * SEGCAP); // 32
  float* y = emb;

  const int tokW  = T_TOK / 4;   // 6400
  const int tiles = T_TOK / 64;  // 400
  const int pgrid = PAIRS / 256; // 200

  seq_ln_kernel<<<tokW, 256, 0, stream>>>(ids, item, pos, ln_w, ln_b, seq);

  // ---- text ----
  gemm_bt_kernel<1><<<tiles, 256, 0, stream>>>(text, ids, nullptr, fct_w, fct_b, emb, 768, 768);
  musgvae_kernel<<<tiles, 256, 0, stream>>>(emb, mu_t_w, mu_t_b, sg_t_w, sg_t_b, t_noise, z);
  gate2_kernel<<<tokW, 256, 0, stream>>>(z, gate_w, gate_b, idx2, pwr, meta);
  scatter_kernel<<<pgrid, 256, 0, stream>>>(idx2, meta, pairs);
  expert_grouped_kernel<<<EGRID, 256, 0, stream>>>(z, texp_w, texp_b, pairs, pwr, meta, tmpT);

  // ---- image ----
  gemm_bt_kernel<1><<<tiles, 256, 0, stream>>>(img, ids, nullptr, fci_w, fci_b, emb, 512, 512);
  musgvae_kernel<<<tiles, 256, 0, stream>>>(emb, mu_i_w, mu_i_b, sg_i_w, sg_i_b, i_noise, z);
  gate2_kernel<<<tokW, 256, 0, stream>>>(z, gate_w, gate_b, idx2, pwr, meta);
  scatter_kernel<<<pgrid, 256, 0, stream>>>(idx2, meta, pairs);
  expert_grouped_kernel<<<EGRID, 256, 0, stream>>>(z, iexp_w, iexp_b, pairs, pwr, meta, tmpI);

  // ---- fusion ----
  gemm_bt_kernel<2><<<tiles, 256, 0, stream>>>(tmpT, nullptr, tmpI, fus_w, fus_b, y, 256, 0);
  fusion_ln_kernel<<<tokW, 256, 0, stream>>>(y, seq, fus_lw, fus_lb, out);
}